// Round 1
// baseline (416.968 us; speedup 1.0000x reference)
//
#include <hip/hip_runtime.h>
#include <math.h>

#define B_SZ 1024
#define K_SZ 24
#define H_SZ 64
#define NVIS 256

// One block per (b, o) output plane. The conv input is a sum of per-channel
// delta functions, so the conv is a scatter of 5x5 weight patches into the
// 64x64 plane. We accumulate in LDS (ds_add_f32 atomics; overlaps between
// channels are possible) and stream the finished tile to HBM with float4
// stores. Total HBM traffic ~= the 402.6 MB output write.
__global__ __launch_bounds__(256) void gs_main(
    const float* __restrict__ x,        // [B,K,2]  (x,y) in [-1.2,1.2]
    const float* __restrict__ w,        // [K,K,5,5] OIHW
    const int*   __restrict__ vis_b,    // [256]
    const int*   __restrict__ vis_k,    // [256]
    float*       __restrict__ out)      // [B,K,64,64]
{
    __shared__ float tile[H_SZ * H_SZ];   // 16 KB
    __shared__ int   spike[K_SZ];         // packed y*64+x, or -1

    const int bid = blockIdx.x;
    const int b   = bid / K_SZ;
    const int o   = bid - b * K_SZ;
    const int tid = threadIdx.x;

    // 1) zero the accumulation tile (16 floats/thread)
#pragma unroll
    for (int i = 0; i < 16; ++i) tile[i * 256 + tid] = 0.0f;

    // 2) compute this batch row's 24 spike positions.
    //    Match jnp.round((x+1.0)*0.5*(H-1)) exactly: same fp op order,
    //    rintf == round-half-to-even == jnp.round.
    if (tid < K_SZ) {
        float fx = x[(b * K_SZ + tid) * 2 + 0];
        float fy = x[(b * K_SZ + tid) * 2 + 1];
        int cx = (int)rintf((fx + 1.0f) * 0.5f * 63.0f);
        int cy = (int)rintf((fy + 1.0f) * 0.5f * 63.0f);
        bool in_range = (cx >= 0) & (cx < H_SZ) & (cy >= 0) & (cy < H_SZ);
        // torch quirk: spike only placed where x-coordinate != 0 (invalid
        // rows were zeroed -> x==0 -> also skipped).
        bool placed = in_range && (cx != 0);
        spike[tid] = placed ? (cy * H_SZ + cx) : -1;
    }
    __syncthreads();

    // 3) kill list: thread t checks vis entry t (256 entries, L2-resident).
    //    Racy same-value (-1) stores are benign.
    {
        int vb = vis_b[tid];
        if (vb == b) spike[vis_k[tid]] = -1;
    }
    __syncthreads();

    // 4) scatter 24 channels x 25 taps = 600 work items.
    //    out[i,j] += w[o,c,di,dj] where i = y+2-di, j = x+2-dj.
    for (int t = tid; t < K_SZ * 25; t += 256) {
        int c = t / 25;
        int p = t - c * 25;
        int s = spike[c];
        if (s >= 0) {
            int y  = s >> 6;
            int xx = s & 63;
            int di = p / 5;
            int dj = p - di * 5;
            int i = y + 2 - di;
            int j = xx + 2 - dj;
            if (((unsigned)i < H_SZ) & ((unsigned)j < H_SZ)) {
                float wv = w[((o * K_SZ + c) * 5 + di) * 5 + dj];
                atomicAdd(&tile[i * H_SZ + j], wv);
            }
        }
    }
    __syncthreads();

    // 5) stream the tile to HBM, coalesced float4 (1024 float4 per plane).
    float4*       o4 = (float4*)(out + (size_t)bid * (H_SZ * H_SZ));
    const float4* t4 = (const float4*)tile;
#pragma unroll
    for (int r = 0; r < 4; ++r) o4[r * 256 + tid] = t4[r * 256 + tid];
}

extern "C" void kernel_launch(void* const* d_in, const int* in_sizes, int n_in,
                              void* d_out, int out_size, void* d_ws, size_t ws_size,
                              hipStream_t stream) {
    const float* x     = (const float*)d_in[0];
    const float* w     = (const float*)d_in[1];
    const int*   vis_b = (const int*)d_in[2];
    const int*   vis_k = (const int*)d_in[3];
    float*       out   = (float*)d_out;

    gs_main<<<B_SZ * K_SZ, 256, 0, stream>>>(x, w, vis_b, vis_k, out);
}

// Round 2
// 401.441 us; speedup vs baseline: 1.0387x; 1.0387x over previous
//
#include <hip/hip_runtime.h>
#include <math.h>

#define B_SZ 1024
#define K_SZ 24
#define H_SZ 64
#define NVIS 256

// ---------------------------------------------------------------------------
// The conv input is a sum of per-(b,c) delta functions, so the whole op is a
// scatter of 5x5 weight patches. Cost model: 402.6 MB of output writes is the
// floor (~65 us at 6.2 TB/s); everything else must hide under it.
//
// Kernel 1 (gs_prep): one thread per (b,k). Computes the spike position with
// the round/in-range/cx!=0 quirks and applies the 256-entry kill list, writing
// a 24576-entry table into d_ws. This removes the dependent x->vis_b->vis_k
// load chain (and ~50 MB of redundant L2 traffic) from every main block.
//
// Kernel 2 (gs_main): one block per (b,o) plane. Global loads (spike slice +
// weight slice, both L2-resident and fully coalesced) are issued FIRST so
// their latency overlaps the LDS zero-fill; then barrier -> <=600 LDS
// atomicAdd scatter -> barrier -> 16 KB coalesced float4 store.
// ---------------------------------------------------------------------------

__global__ __launch_bounds__(256) void gs_prep(
    const float2* __restrict__ x,      // [B*K] (x,y)
    const int*    __restrict__ vis_b,  // [256]
    const int*    __restrict__ vis_k,  // [256]
    int*          __restrict__ spike_tab) // [B*K] packed y*64+x or -1
{
    const int bk = blockIdx.x * 256 + threadIdx.x;   // exactly B*K threads
    const int b  = bk / K_SZ;
    const int k  = bk - b * K_SZ;
    const float2 c = x[bk];
    // match jnp.round((v+1.0)*0.5*(H-1)): same op order, rintf = half-to-even
    const int cx = (int)rintf((c.x + 1.0f) * 0.5f * 63.0f);
    const int cy = (int)rintf((c.y + 1.0f) * 0.5f * 63.0f);
    // in-range AND the torch quirk (x-coord != 0) => cx in [1,64)
    const bool ok = (cx >= 1) & (cx < H_SZ) & (cy >= 0) & (cy < H_SZ);
    int s = ok ? (cy * H_SZ + cx) : -1;
    // kill list: vis arrays are wave-uniform loads (s_load), 256 iterations
    for (int i = 0; i < NVIS; ++i) {
        if ((vis_b[i] == b) & (vis_k[i] == k)) s = -1;
    }
    spike_tab[bk] = s;
}

__global__ __launch_bounds__(256) void gs_main(
    const int*   __restrict__ spike_tab, // [B*K]
    const float* __restrict__ w,         // [K,K,5,5] OIHW, slice per o = 600 f
    float*       __restrict__ out)       // [B,K,64,64]
{
    __shared__ float tile[H_SZ * H_SZ];  // 16 KB
    const int bid = blockIdx.x;
    const int b   = bid / K_SZ;
    const int o   = bid - b * K_SZ;
    const int tid = threadIdx.x;

    // Issue the scatter-phase global loads up front: latency overlaps zeroing.
    const int*   sp = spike_tab + b * K_SZ;
    const float* wo = w + o * (K_SZ * 25);
    int   sv[3]; float wv[3]; int pp[3];
    #pragma unroll
    for (int it = 0; it < 3; ++it) {
        const int t = tid + it * 256;
        if (t < K_SZ * 25) {
            const int c = t / 25;
            pp[it] = t - c * 25;
            sv[it] = sp[c];        // <=3 cache lines, broadcast within wave
            wv[it] = wo[t];        // fully coalesced
        } else {
            sv[it] = -1;
        }
    }

    // Zero the accumulation tile with b128 stores.
    float4* t4 = (float4*)tile;
    const float4 z = make_float4(0.f, 0.f, 0.f, 0.f);
    #pragma unroll
    for (int r = 0; r < 4; ++r) t4[r * 256 + tid] = z;
    __syncthreads();

    // Scatter <=600 taps: out[i,j] += w[o,c,di,dj], i=y+2-di, j=x+2-dj.
    #pragma unroll
    for (int it = 0; it < 3; ++it) {
        const int s = sv[it];
        if (s >= 0) {
            const int y  = s >> 6;
            const int xx = s & 63;
            const int di = pp[it] / 5;
            const int dj = pp[it] - di * 5;
            const int i  = y + 2 - di;
            const int j  = xx + 2 - dj;
            if (((unsigned)i < H_SZ) & ((unsigned)j < H_SZ))
                atomicAdd(&tile[i * H_SZ + j], wv[it]);
        }
    }
    __syncthreads();

    // Stream the finished 16 KB plane out, coalesced float4.
    float4* o4 = (float4*)(out + (size_t)bid * (H_SZ * H_SZ));
    #pragma unroll
    for (int r = 0; r < 4; ++r) o4[r * 256 + tid] = t4[r * 256 + tid];
}

extern "C" void kernel_launch(void* const* d_in, const int* in_sizes, int n_in,
                              void* d_out, int out_size, void* d_ws, size_t ws_size,
                              hipStream_t stream) {
    const float2* x     = (const float2*)d_in[0];
    const float*  w     = (const float*)d_in[1];
    const int*    vis_b = (const int*)d_in[2];
    const int*    vis_k = (const int*)d_in[3];
    float*        out   = (float*)d_out;
    int*          spike_tab = (int*)d_ws;   // 24576 * 4 B = 96 KB scratch

    gs_prep<<<(B_SZ * K_SZ) / 256, 256, 0, stream>>>(x, vis_b, vis_k, spike_tab);
    gs_main<<<B_SZ * K_SZ, 256, 0, stream>>>(spike_tab, w, out);
}